// Round 5
// baseline (1210.601 us; speedup 1.0000x reference)
//
#include <hip/hip_runtime.h>
#include <cmath>

// Problem constants
#define S_LEN 2048
#define HID 4096
#define NHEAD 32
#define Q_LORA 1536
#define KV_LORA 512
#define NOPE 128
#define ROPE_D 64
#define VDIM 128
#define QK_DIM 192       // NOPE + ROPE
#define FUSED_N 2112     // Q_LORA + KV_LORA + ROPE
#define FUSED_NPAD 2176  // padded to a multiple of 128

typedef __attribute__((ext_vector_type(8))) short short8;
typedef __attribute__((ext_vector_type(4))) float floatx4;
typedef unsigned short ushort_t;

// float -> bf16 bits, round-to-nearest-even
__device__ inline short f2bf(float f) {
    union { float f; unsigned u; } v; v.f = f;
    unsigned r = (v.u + 0x7fffu + ((v.u >> 16) & 1u)) >> 16;
    return (short)r;
}
__device__ inline float bf2f(ushort_t u) {
    union { unsigned u; float f; } v; v.u = ((unsigned)u) << 16; return v.f;
}

// async 16B global -> LDS (LDS dest: wave-uniform base + lane*16)
#define GLOAD16(g, l)                                                        \
    __builtin_amdgcn_global_load_lds(                                        \
        (const __attribute__((address_space(1))) unsigned int*)(g),          \
        (__attribute__((address_space(3))) unsigned int*)(l), 16, 0, 0)

// ---------------------------------------------------------------------------
// fp32 -> bf16 converters (n % 8 == 0)
// ---------------------------------------------------------------------------
__global__ __launch_bounds__(256) void conv_bf16(
    const float* __restrict__ src, ushort_t* __restrict__ dst, int n)
{
    int i = (blockIdx.x * 256 + threadIdx.x) * 8;
    if (i >= n) return;
    const float4* s = (const float4*)(src + i);
    float4 a = s[0], b = s[1];
    short8 v;
    v[0] = f2bf(a.x); v[1] = f2bf(a.y); v[2] = f2bf(a.z); v[3] = f2bf(a.w);
    v[4] = f2bf(b.x); v[5] = f2bf(b.y); v[6] = f2bf(b.z); v[7] = f2bf(b.w);
    *(short8*)(dst + i) = v;
}

__global__ __launch_bounds__(256) void conv_bf16_pad(
    const float* __restrict__ src, ushort_t* __restrict__ dst, int n_src, int n_tot)
{
    int i = (blockIdx.x * 256 + threadIdx.x) * 8;
    if (i >= n_tot) return;
    short8 v;
    if (i < n_src) {
        const float4* s = (const float4*)(src + i);
        float4 a = s[0], b = s[1];
        v[0] = f2bf(a.x); v[1] = f2bf(a.y); v[2] = f2bf(a.z); v[3] = f2bf(a.w);
        v[4] = f2bf(b.x); v[5] = f2bf(b.y); v[6] = f2bf(b.z); v[7] = f2bf(b.w);
    } else {
        v = (short8){0,0,0,0,0,0,0,0};
    }
    *(short8*)(dst + i) = v;
}

// ---------------------------------------------------------------------------
// bf16 MFMA GEMM (m97 structure): C(M,N) = A(M,K) * B(N,K)^T   (verified r4)
// ---------------------------------------------------------------------------
__device__ inline void store_c(float* p, float v)    { *p = v; }
__device__ inline void store_c(ushort_t* p, float v) { *p = (ushort_t)f2bf(v); }

template <typename CT>
__global__ __launch_bounds__(256) void gemm_bf16(
    const ushort_t* __restrict__ A, int lda,
    const ushort_t* __restrict__ B, int ldb,
    CT* __restrict__ C, int ldc, int N, int K)
{
    __shared__ short8 As8[512];   // 8 KB
    __shared__ short8 Bs8[512];   // 8 KB

    const int tid  = threadIdx.x;
    const int lane = tid & 63;
    const int wave = tid >> 6;
    const int m    = lane & 15;
    const int quad = lane >> 4;
    const int wr   = wave >> 1, wc = wave & 1;
    const int m0 = blockIdx.y * 128;
    const int n0 = blockIdx.x * 128;

    floatx4 acc[4][4];
    #pragma unroll
    for (int i = 0; i < 4; ++i)
        #pragma unroll
        for (int j = 0; j < 4; ++j) acc[i][j] = (floatx4){0.f, 0.f, 0.f, 0.f};

    const int R0 = tid >> 6, q0s = (tid >> 4) & 3, e0 = tid & 15;
    const int R1 = (tid + 256) >> 6, q1s = ((tid + 256) >> 4) & 3, e1 = (tid + 256) & 15;

    for (int k0 = 0; k0 < K; k0 += 32) {
        __syncthreads();
        GLOAD16(A + (size_t)(m0 + R0 * 16 + e0) * lda + k0 + q0s * 8, &As8[tid]);
        GLOAD16(A + (size_t)(m0 + R1 * 16 + e1) * lda + k0 + q1s * 8, &As8[tid + 256]);
        GLOAD16(B + (size_t)(n0 + R0 * 16 + e0) * ldb + k0 + q0s * 8, &Bs8[tid]);
        GLOAD16(B + (size_t)(n0 + R1 * 16 + e1) * ldb + k0 + q1s * 8, &Bs8[tid + 256]);
        __syncthreads();

        short8 af[4], bfr[4];
        #pragma unroll
        for (int i = 0; i < 4; ++i) af[i]  = As8[((wr * 4 + i) * 4 + quad) * 16 + m];
        #pragma unroll
        for (int i = 0; i < 4; ++i) bfr[i] = Bs8[((wc * 4 + i) * 4 + quad) * 16 + m];

        #pragma unroll
        for (int ri = 0; ri < 4; ++ri)
            #pragma unroll
            for (int ci = 0; ci < 4; ++ci)
                acc[ri][ci] = __builtin_amdgcn_mfma_f32_16x16x32_bf16(
                    af[ri], bfr[ci], acc[ri][ci], 0, 0, 0);
    }

    #pragma unroll
    for (int ci = 0; ci < 4; ++ci) {
        int col = n0 + wc * 64 + ci * 16 + m;
        if (col < N) {
            #pragma unroll
            for (int ri = 0; ri < 4; ++ri) {
                int row = m0 + wr * 64 + ri * 16 + quad * 4;
                #pragma unroll
                for (int r = 0; r < 4; ++r)
                    store_c(&C[(size_t)(row + r) * ldc + col], acc[ri][ci][r]);
            }
        }
    }
}

// ---------------------------------------------------------------------------
// RMSNorm(cq), RMSNorm(ckv), RoPE on k_pe — in place on bf16 a (S, 2112).
// ---------------------------------------------------------------------------
__global__ __launch_bounds__(256) void norm_rope_kernel(
    ushort_t* __restrict__ a,
    const float* __restrict__ q_ln_w,
    const float* __restrict__ kv_ln_w,
    const int* __restrict__ pos_ids)
{
    const int s = blockIdx.x;
    ushort_t* row = a + (size_t)s * FUSED_N;
    __shared__ float red[256];
    const int tid = threadIdx.x;

    float ss = 0.f;
    for (int i = tid; i < Q_LORA; i += 256) { float v = bf2f(row[i]); ss += v * v; }
    red[tid] = ss;
    __syncthreads();
    for (int w = 128; w > 0; w >>= 1) {
        if (tid < w) red[tid] += red[tid + w];
        __syncthreads();
    }
    float scale_q = rsqrtf(red[0] / (float)Q_LORA + 1e-6f);
    __syncthreads();
    for (int i = tid; i < Q_LORA; i += 256)
        row[i] = (ushort_t)f2bf(bf2f(row[i]) * scale_q * q_ln_w[i]);
    __syncthreads();

    ss = 0.f;
    for (int i = tid; i < KV_LORA; i += 256) { float v = bf2f(row[Q_LORA + i]); ss += v * v; }
    red[tid] = ss;
    __syncthreads();
    for (int w = 128; w > 0; w >>= 1) {
        if (tid < w) red[tid] += red[tid + w];
        __syncthreads();
    }
    float scale_kv = rsqrtf(red[0] / (float)KV_LORA + 1e-6f);
    __syncthreads();
    for (int i = tid; i < KV_LORA; i += 256)
        row[Q_LORA + i] = (ushort_t)f2bf(bf2f(row[Q_LORA + i]) * scale_kv * kv_ln_w[i]);

    if (tid < 32) {
        const int j = tid;
        float pos = (float)pos_ids[s];
        float inv_freq = expf(-(float)j * (9.210340371976184f / 32.f));
        float ang = pos * inv_freq;
        float c = cosf(ang), sn = sinf(ang);
        float x1 = bf2f(row[Q_LORA + KV_LORA + j]);
        float x2 = bf2f(row[Q_LORA + KV_LORA + 32 + j]);
        row[Q_LORA + KV_LORA + j]      = (ushort_t)f2bf(x1 * c - x2 * sn);
        row[Q_LORA + KV_LORA + 32 + j] = (ushort_t)f2bf(x2 * c + x1 * sn);
    }
}

// ---------------------------------------------------------------------------
// RoPE on q_pe (bf16 in place)
// ---------------------------------------------------------------------------
__global__ __launch_bounds__(256) void rope_q_kernel(
    ushort_t* __restrict__ q, const int* __restrict__ pos_ids)
{
    int idx = blockIdx.x * blockDim.x + threadIdx.x;
    if (idx >= S_LEN * NHEAD) return;
    int s = idx >> 5;
    float pos = (float)pos_ids[s];
    ushort_t* qp = q + (size_t)idx * QK_DIM + NOPE;
    #pragma unroll 4
    for (int j = 0; j < 32; ++j) {
        float inv_freq = expf(-(float)j * (9.210340371976184f / 32.f));
        float ang = pos * inv_freq;
        float c = cosf(ang), sn = sinf(ang);
        float x1 = bf2f(qp[j]), x2 = bf2f(qp[32 + j]);
        qp[j]      = (ushort_t)f2bf(x1 * c - x2 * sn);
        qp[32 + j] = (ushort_t)f2bf(x2 * c + x1 * sn);
    }
}

// ---------------------------------------------------------------------------
// V transpose: vt[h][d][s] = kv[s][h][128+d].  64x64 tiles via LDS.
// grid (S/64, 128/64, H), 256 threads.
// ---------------------------------------------------------------------------
__global__ __launch_bounds__(256) void v_transpose(
    const ushort_t* __restrict__ kv, ushort_t* __restrict__ vt)
{
    __shared__ ushort_t tile[64][68];
    const int tid = threadIdx.x;
    const int s0 = blockIdx.x * 64;
    const int d0 = blockIdx.y * 64;
    const int h  = blockIdx.z;

    {
        int sl = tid >> 3, d8 = (tid & 7) * 8;
        #pragma unroll
        for (int rep = 0; rep < 2; ++rep) {
            int s = sl + rep * 32;
            short8 v = *(const short8*)(kv + ((size_t)(s0 + s) * NHEAD + h) * 256 + 128 + d0 + d8);
            *(short8*)&tile[s][d8] = v;
        }
    }
    __syncthreads();
    {
        int dl = tid >> 3, s8 = (tid & 7) * 8;
        #pragma unroll
        for (int rep = 0; rep < 2; ++rep) {
            int d = dl + rep * 32;
            short8 v;
            #pragma unroll
            for (int j = 0; j < 8; ++j) v[j] = (short)tile[s8 + j][d];
            *(short8*)(vt + ((size_t)h * 128 + d0 + d) * S_LEN + s0 + s8) = v;
        }
    }
}

// ---------------------------------------------------------------------------
// Barrier-free MFMA bf16 flash attention (causal).
//   q:    (S, H, 192) bf16 roped      kv: (S, H, 256) bf16 [k_nope | v]
//   abuf: (S, 2112) bf16, k_pe at 2048
//   vt:   (H, 128, S) bf16 (V transposed)
//   attn: (S, H, 128) bf16
// 4 independent waves/block, wave owns 16 Q rows; K/k_pe/V^T fragments are
// 16B-contiguous -> direct global loads (L2-backed), NO __syncthreads.
// Only LDS: per-wave 1KB P round-trip (C-layout -> A-layout).
// Q-tiles dispatched longest-first for causal load balance.
// ---------------------------------------------------------------------------
__global__ __launch_bounds__(256) void attn_mfma(
    const ushort_t* __restrict__ q,
    const ushort_t* __restrict__ kv,
    const ushort_t* __restrict__ abuf,
    const ushort_t* __restrict__ vt,
    ushort_t* __restrict__ attn)
{
    __shared__ short8 PA[256];   // 4 KB: 64 short8 per wave

    const int tid  = threadIdx.x;
    const int wave = tid >> 6;
    const int lane = tid & 63;
    const int m    = lane & 15;
    const int quad = lane >> 4;
    const int h    = blockIdx.y;
    const int q0   = (gridDim.x - 1 - blockIdx.x) * 64;   // longest first
    const int qrow_base = q0 + wave * 16;

    // Q fragments: 6 chunks of 16x32, direct 16B loads
    short8 qf[6];
    {
        const ushort_t* qrow = q + ((size_t)(qrow_base + m) * NHEAD + h) * QK_DIM;
        #pragma unroll
        for (int c = 0; c < 6; ++c)
            qf[c] = *(const short8*)(qrow + c * 32 + quad * 8);
    }

    floatx4 O[8];
    #pragma unroll
    for (int t = 0; t < 8; ++t) O[t] = (floatx4){0.f, 0.f, 0.f, 0.f};
    float mrow[4] = {-1e30f, -1e30f, -1e30f, -1e30f};
    float lrow[4] = {0.f, 0.f, 0.f, 0.f};

    const float scale = 0.07216878364870323f; // 1/sqrt(192)
    const int ntile = (qrow_base + 47) >> 5;  // keys 0 .. qrow_base+15
    short*  pas = (short*)PA + wave * 512;
    short8* paf = PA + wave * 64;

    const ushort_t* vbase = vt + ((size_t)h * 128 + m) * S_LEN + quad * 8;

    for (int tt = 0; tt < ntile; ++tt) {
        const int t0 = tt * 32;

        // ---- QK^T: direct global B-fragments (keys t0+m and t0+16+m) ----
        const ushort_t* krow0 = kv + ((size_t)(t0 + m) * NHEAD + h) * 256 + quad * 8;
        const ushort_t* krow1 = krow0 + (size_t)16 * NHEAD * 256;
        const ushort_t* perow0 = abuf + (size_t)(t0 + m) * FUSED_N + 2048 + quad * 8;
        const ushort_t* perow1 = perow0 + (size_t)16 * FUSED_N;

        floatx4 s0 = (floatx4){0.f, 0.f, 0.f, 0.f};
        floatx4 s1 = (floatx4){0.f, 0.f, 0.f, 0.f};
        #pragma unroll
        for (int c = 0; c < 4; ++c) {
            s0 = __builtin_amdgcn_mfma_f32_16x16x32_bf16(qf[c], *(const short8*)(krow0 + c * 32), s0, 0, 0, 0);
            s1 = __builtin_amdgcn_mfma_f32_16x16x32_bf16(qf[c], *(const short8*)(krow1 + c * 32), s1, 0, 0, 0);
        }
        #pragma unroll
        for (int c = 0; c < 2; ++c) {
            s0 = __builtin_amdgcn_mfma_f32_16x16x32_bf16(qf[4 + c], *(const short8*)(perow0 + c * 32), s0, 0, 0, 0);
            s1 = __builtin_amdgcn_mfma_f32_16x16x32_bf16(qf[4 + c], *(const short8*)(perow1 + c * 32), s1, 0, 0, 0);
        }

        // ---- mask + online softmax (C layout: row=quad*4+r, col=m) ----
        const int qb = qrow_base + quad * 4;
        float sv0[4], sv1[4];
        #pragma unroll
        for (int r = 0; r < 4; ++r) {
            float a0 = s0[r] * scale;
            float a1 = s1[r] * scale;
            if (t0 + m > qb + r)      a0 = -1e30f;
            if (t0 + 16 + m > qb + r) a1 = -1e30f;
            sv0[r] = a0; sv1[r] = a1;
        }
        #pragma unroll
        for (int r = 0; r < 4; ++r) {
            float v = fmaxf(sv0[r], sv1[r]);
            v = fmaxf(v, __shfl_xor(v, 1));
            v = fmaxf(v, __shfl_xor(v, 2));
            v = fmaxf(v, __shfl_xor(v, 4));
            v = fmaxf(v, __shfl_xor(v, 8));
            float mnew  = fmaxf(mrow[r], v);
            float alpha = __expf(mrow[r] - mnew);
            float p0 = __expf(sv0[r] - mnew);
            float p1 = __expf(sv1[r] - mnew);
            float rs = p0 + p1;
            rs += __shfl_xor(rs, 1);
            rs += __shfl_xor(rs, 2);
            rs += __shfl_xor(rs, 4);
            rs += __shfl_xor(rs, 8);
            lrow[r] = lrow[r] * alpha + rs;
            mrow[r] = mnew;
            #pragma unroll
            for (int t = 0; t < 8; ++t) O[t][r] *= alpha;
            // P: C-layout (row, key=m / m+16) -> A-layout LDS
            int row = quad * 4 + r;
            pas[((m >> 3) + 0) * 128 + row * 8 + (m & 7)] = f2bf(p0);
            pas[((m >> 3) + 2) * 128 + row * 8 + (m & 7)] = f2bf(p1);
        }

        // ---- PV: B-fragments direct from V^T ----
        short8 pfrag = paf[quad * 16 + m];
        const ushort_t* vb = vbase + t0;
        #pragma unroll
        for (int t = 0; t < 8; ++t) {
            O[t] = __builtin_amdgcn_mfma_f32_16x16x32_bf16(
                pfrag, *(const short8*)(vb + (size_t)(16 * t) * S_LEN), O[t], 0, 0, 0);
        }
    }

    // ---- epilogue ----
    #pragma unroll
    for (int r = 0; r < 4; ++r) {
        float linv = 1.f / lrow[r];
        int row = qrow_base + quad * 4 + r;
        ushort_t* dst = attn + ((size_t)row * NHEAD + h) * VDIM + m;
        #pragma unroll
        for (int t = 0; t < 8; ++t)
            dst[16 * t] = (ushort_t)f2bf(O[t][r] * linv);
    }
}

// ---------------------------------------------------------------------------
extern "C" void kernel_launch(void* const* d_in, const int* in_sizes, int n_in,
                              void* d_out, int out_size, void* d_ws, size_t ws_size,
                              hipStream_t stream)
{
    const int*   pos    = (const int*)d_in[0];
    const float* hs     = (const float*)d_in[1];
    const float* w_a    = (const float*)d_in[2];
    const float* qlnw   = (const float*)d_in[3];
    const float* kvlnw  = (const float*)d_in[4];
    const float* w_qb   = (const float*)d_in[5];
    const float* w_kvb  = (const float*)d_in[6];
    const float* w_o    = (const float*)d_in[7];
    float* out = (float*)d_out;

    // workspace: 162.8 MB (< 168.3 MB proven available in rounds 0-2)
    char* p = (char*)d_ws;
    ushort_t* a_bf    = (ushort_t*)p; p += (size_t)S_LEN * FUSED_N * 2;          //  8.65 MB
    ushort_t* q_bf    = (ushort_t*)p; p += (size_t)S_LEN * NHEAD * QK_DIM * 2;   // 25.2 MB
    ushort_t* kv_bf   = (ushort_t*)p; p += (size_t)S_LEN * NHEAD * 256 * 2;      // 33.6 MB
    ushort_t* attn_bf = (ushort_t*)p; p += (size_t)S_LEN * HID * 2;              // 16.8 MB
    ushort_t* vt_bf   = (ushort_t*)p; p += (size_t)NHEAD * VDIM * S_LEN * 2;     // 16.8 MB
    ushort_t* hs_bf   = (ushort_t*)p; p += (size_t)S_LEN * HID * 2;              // 16.8 MB
    ushort_t* w_a_bf  = (ushort_t*)p; p += (size_t)FUSED_NPAD * HID * 2;         // 17.8 MB
    ushort_t* w_qb_bf = (ushort_t*)p; p += (size_t)NHEAD * QK_DIM * Q_LORA * 2;  // 18.9 MB
    ushort_t* w_kvb_bf= (ushort_t*)p; p += (size_t)NHEAD * 256 * KV_LORA * 2;    //  8.4 MB
    // w_o_bf (33.6 MB) aliases hs_bf + w_a_bf (34.6 MB), dead after gemm 1
    ushort_t* w_o_bf  = hs_bf;

    if (ws_size < (size_t)(p - (char*)d_ws)) return;  // fail loud, not fault

    dim3 blk(256);
    auto cgrid = [](size_t n) { return dim3((unsigned)((n / 8 + 255) / 256)); };

    // 0. fp32 -> bf16 (hs + weights for gemms 1,3,4)
    conv_bf16<<<cgrid((size_t)S_LEN * HID), blk, 0, stream>>>(hs, hs_bf, S_LEN * HID);
    conv_bf16_pad<<<cgrid((size_t)FUSED_NPAD * HID), blk, 0, stream>>>(
        w_a, w_a_bf, FUSED_N * HID, FUSED_NPAD * HID);
    conv_bf16<<<cgrid((size_t)NHEAD * QK_DIM * Q_LORA), blk, 0, stream>>>(
        w_qb, w_qb_bf, NHEAD * QK_DIM * Q_LORA);
    conv_bf16<<<cgrid((size_t)NHEAD * 256 * KV_LORA), blk, 0, stream>>>(
        w_kvb, w_kvb_bf, NHEAD * 256 * KV_LORA);

    // 1. a = hs @ w_fused_a^T : (2048, 2112) bf16, K=4096
    gemm_bf16<ushort_t><<<dim3(FUSED_NPAD / 128, S_LEN / 128), blk, 0, stream>>>(
        hs_bf, HID, w_a_bf, HID, a_bf, FUSED_N, FUSED_N, HID);

    // 1b. w_o -> bf16 (into region freed by gemm 1)
    conv_bf16<<<cgrid((size_t)HID * HID), blk, 0, stream>>>(w_o, w_o_bf, HID * HID);

    // 2. RMSNorm cq / ckv + k_pe RoPE (in place, bf16)
    norm_rope_kernel<<<S_LEN, 256, 0, stream>>>(a_bf, qlnw, kvlnw, pos);

    // 3. q = cq @ w_q_b^T : (2048, 6144) bf16, K=1536
    gemm_bf16<ushort_t><<<dim3(NHEAD * QK_DIM / 128, S_LEN / 128), blk, 0, stream>>>(
        a_bf, FUSED_N, w_qb_bf, Q_LORA, q_bf, NHEAD * QK_DIM, NHEAD * QK_DIM, Q_LORA);

    // 4. kv = ckv @ w_kv_b^T : (2048, 8192) bf16, K=512
    gemm_bf16<ushort_t><<<dim3(NHEAD * 256 / 128, S_LEN / 128), blk, 0, stream>>>(
        a_bf + Q_LORA, FUSED_N, w_kvb_bf, KV_LORA, kv_bf, NHEAD * 256, NHEAD * 256, KV_LORA);

    // 4b. V transpose -> vt (H, 128, S)
    v_transpose<<<dim3(S_LEN / 64, VDIM / 64, NHEAD), blk, 0, stream>>>(kv_bf, vt_bf);

    // 5. RoPE on q_pe (bf16 in place)
    rope_q_kernel<<<(S_LEN * NHEAD + 255) / 256, 256, 0, stream>>>(q_bf, pos);

    // 6. barrier-free MFMA flash attention -> attn (2048, 32, 128) bf16
    attn_mfma<<<dim3(S_LEN / 64, NHEAD), blk, 0, stream>>>(
        q_bf, kv_bf, a_bf, vt_bf, attn_bf);

    // 7. out = attn @ w_o^T : (2048, 4096) fp32, K=4096
    gemm_bf16<float><<<dim3(HID / 128, S_LEN / 128), blk, 0, stream>>>(
        attn_bf, HID, w_o_bf, HID, out, HID, HID, HID);
}